// Round 2
// baseline (806.884 us; speedup 1.0000x reference)
//
#include <hip/hip_runtime.h>

#define HH 128
#define WW 128
#define CC 64
#define ROW (WW*CC)   // 8192 floats per (b,h) row

// ---------------------------------------------------------------------------
// relu(bn(src)) with transpose [b,h,w,c] -> [b,h,c,w]  (one block per row)
// ---------------------------------------------------------------------------
__global__ __launch_bounds__(256, 8)
void bn_relu_transpose(const float* __restrict__ src, float* __restrict__ dst,
                       const float* __restrict__ gma, const float* __restrict__ bta,
                       const float* __restrict__ mu,  const float* __restrict__ var)
{
    __shared__ float tile[WW*65];          // +1 pad: conflict-free transposed reads
    __shared__ float sc[CC], bi[CC];
    const int t = threadIdx.x;
    if (t < CC) {
        float s = gma[t] * rsqrtf(var[t] + 1e-3f);
        sc[t] = s;
        bi[t] = bta[t] - mu[t]*s;
    }
    __syncthreads();
    const size_t row = blockIdx.x;         // b*128 + h
    const float* sp = src + row*ROW;
    for (int k = 0; k < 8; ++k) {
        int o = t*4 + k*1024;
        float4 v = *(const float4*)(sp + o);
        int w = o >> 6, c = o & 63;
        tile[w*65+c+0] = fmaxf(0.f, v.x*sc[c+0] + bi[c+0]);
        tile[w*65+c+1] = fmaxf(0.f, v.y*sc[c+1] + bi[c+1]);
        tile[w*65+c+2] = fmaxf(0.f, v.z*sc[c+2] + bi[c+2]);
        tile[w*65+c+3] = fmaxf(0.f, v.w*sc[c+3] + bi[c+3]);
    }
    __syncthreads();
    float* dp = dst + row*ROW;
    // FIX(R1->R2): previous version iterated k<8 with stride 1024, writing only
    // 2048 of 8192 elements (75% left as poison). Now 32 x 256 covers all.
    // o = c*128 + w: lane->w consecutive => coalesced store; LDS read stride 65
    // per lane => conflict-free.
    for (int k = 0; k < 32; ++k) {
        int o = t + k*256;
        int c = o >> 7, w = o & 127;
        dp[o] = tile[w*65+c];
    }
}

// ---------------------------------------------------------------------------
// 3x3 SAME conv (zero pad), srcT is [b,h,c,w], weights HWIO [3][3][64][64],
// dst is [b,h,w,c]. One thread = one output pixel, all 64 couts.
// Weight indices are wave-uniform -> s_load (SMEM pipe); input reads are
// lane->w coalesced dword loads (L1-resident); inner body = 64 v_fma.
// ---------------------------------------------------------------------------
__global__ __launch_bounds__(256, 4)
void conv3x3(const float* __restrict__ srcT, const float* __restrict__ wgt,
             float* __restrict__ dst)
{
    const int blk = blockIdx.x;            // b*64 + i0  (2 rows per block)
    const int b = blk >> 6, i0 = blk & 63;
    const int r = threadIdx.x >> 7;        // wave-uniform row select
    const int w = threadIdx.x & 127;
    const int i = i0*2 + r;
    const float* sbase = srcT + (size_t)b * (HH*ROW);
    float acc[CC];
    #pragma unroll
    for (int k = 0; k < CC; ++k) acc[k] = 0.f;
    for (int di = 0; di < 3; ++di) {
        int iy = i + di - 1;
        if (iy < 0 || iy >= HH) continue;  // zero pad rows (uniform branch)
        const float* rowp = sbase + (size_t)iy * ROW;   // [c][w]
        for (int dj = 0; dj < 3; ++dj) {
            int wx = w + dj - 1;
            bool ok = (wx >= 0) && (wx < WW);
            int wxc = ok ? wx : 0;
            const float* wp = wgt + ((di*3 + dj) << 12);    // [cin][cout]
            #pragma unroll 2
            for (int cin = 0; cin < CC; ++cin) {
                float iv = rowp[(cin << 7) + wxc];
                iv = ok ? iv : 0.f;        // zero pad columns
                const float* wr = wp + (cin << 6);
                #pragma unroll
                for (int co = 0; co < CC; ++co)
                    acc[co] = fmaf(iv, wr[co], acc[co]);
            }
        }
    }
    float* dp = dst + (((size_t)b*HH + i)*WW + w) * CC;
    #pragma unroll
    for (int k = 0; k < 16; ++k)
        ((float4*)dp)[k] = make_float4(acc[4*k], acc[4*k+1], acc[4*k+2], acc[4*k+3]);
}

// ---------------------------------------------------------------------------
// Sobel coefficients + K=5 diffusion + relu(bn_o). One block per (b,h) row.
// Rolls are cyclic on W and C only -> row-local. Sobel uses REFLECT rows i+-1.
// h lives in LDS (sA); all per-element coefficients in registers.
// ---------------------------------------------------------------------------
__global__ __launch_bounds__(1024, 4)
void diffuse(const float* __restrict__ f, const float* __restrict__ g,
             float* __restrict__ out,
             const float* __restrict__ bog, const float* __restrict__ bob,
             const float* __restrict__ bom, const float* __restrict__ bov)
{
    __shared__ float sA[ROW], sB[ROW];     // 64 KB total -> 2 blocks/CU
    const int t = threadIdx.x;
    const int rowb = blockIdx.x;           // b*128 + i
    const int b = rowb >> 7, i = rowb & 127;
    const int im = (i == 0)    ? 1    : i - 1;   // reflect (jnp.pad 'reflect')
    const int ip = (i == HH-1) ? HH-2 : i + 1;
    const float* fb  = f + (size_t)b * (HH*ROW);
    const float* frm = fb + (size_t)im * ROW;
    const float* fr0 = fb + (size_t)i  * ROW;
    const float* frp = fb + (size_t)ip * ROW;
    const float* gr  = g + (size_t)rowb * ROW;

    // stage 1: sA = f[i-1], sB = f[i+1]
    for (int k = 0; k < 2; ++k) {
        int o = (t + k*1024) * 4;
        *(float4*)(sA + o) = *(const float4*)(frm + o);
        *(float4*)(sB + o) = *(const float4*)(frp + o);
    }
    __syncthreads();

    float dy8[8], dxp8[8];
    #pragma unroll
    for (int k = 0; k < 8; ++k) {
        int e = t + (k << 10);
        int w = e >> 6, c = e & 63;
        int wm  = (w == 0)    ? 1    : w - 1;    // reflect in W (sobel only)
        int wpp = (w == WW-1) ? WW-2 : w + 1;
        float amm = sA[wm*CC+c], am0 = sA[w*CC+c], amp = sA[wpp*CC+c];
        float bmm = sB[wm*CC+c], bm0 = sB[w*CC+c], bmp = sB[wpp*CC+c];
        dy8[k]  = (bmm + 2.f*bm0 + bmp) - (amm + 2.f*am0 + amp);
        dxp8[k] = (amp - amm) + (bmp - bmm);     // dx partial from rows i+-1
    }
    __syncthreads();

    // stage 2: sA = f[i] (becomes h), sB = g[i]
    for (int k = 0; k < 2; ++k) {
        int o = (t + k*1024) * 4;
        *(float4*)(sA + o) = *(const float4*)(fr0 + o);
        *(float4*)(sB + o) = *(const float4*)(gr + o);
    }
    __syncthreads();

    float cH0[8], cEE[8], cWm[8], cWp[8], cCm[8], cCp[8], cF[8], h0[8], h[8];
    #pragma unroll
    for (int k = 0; k < 8; ++k) {
        int e = t + (k << 10);
        int w = e >> 6, c = e & 63;
        int wm  = (w == 0)    ? 1    : w - 1;
        int wpp = (w == WW-1) ? WW-2 : w + 1;
        float fwm = sA[wm*CC+c], fv = sA[w*CC+c], fwp = sA[wpp*CC+c];
        float dx = dxp8[k] + 2.f*(fwp - fwm);
        float dy = dy8[k];
        float Bx = 0.2f / (dy*dy*0.25f + 1.f);   // Dx*DT, LAM2=4
        float By = 0.2f / (dx*dx*0.25f + 1.f);   // Dy*DT
        float gv = sB[w*CC+c];
        float A  = gv * 0.2f;                    // Ax = Ay = g*DT
        float gl  = sB[((w+WW-1)&(WW-1))*CC + c];   // cyclic rolls
        float grr = sB[((w+1)   &(WW-1))*CC + c];
        float gd  = sB[w*CC + ((c+CC-1)&(CC-1))];
        float gu  = sB[w*CC + ((c+1)   &(CC-1))];
        float E  = ((gl - grr) + (gd - gu)) * 0.5f * 0.2f;  // (ux+vy)*DT
        float Dd = 1.f / (1.f + 2.f*Bx + 2.f*By);
        cH0[k] = Dd * (1.f - 2.f*Bx - 2.f*By);
        cEE[k] = -2.f * E * Dd;
        cWm[k] = Dd * (2.f*Bx - A);   // coeff of h[w-1]
        cWp[k] = Dd * (2.f*Bx + A);   // coeff of h[w+1]
        cCm[k] = Dd * (2.f*By - A);   // coeff of h[c-1]
        cCp[k] = Dd * (2.f*By + A);   // coeff of h[c+1]
        cF[k]  = Dd * 0.4f * fv;      // D * 2*DT*f
        h0[k] = fv; h[k] = fv;        // leapfrog init: h = h0 = f
    }

    float* sh = sA;                    // h array aliases f[i] (h init == f)
    for (int it = 0; it < 5; ++it) {
        float hn[8];
        #pragma unroll
        for (int k = 0; k < 8; ++k) {
            int e = t + (k << 10);
            int w = e >> 6, c = e & 63;
            float hl = sh[((w+WW-1)&(WW-1))*CC + c];
            float hr = sh[((w+1)   &(WW-1))*CC + c];
            float hd = sh[w*CC + ((c+CC-1)&(CC-1))];
            float hu = sh[w*CC + ((c+1)   &(CC-1))];
            hn[k] = cH0[k]*h0[k] + cEE[k]*h[k] + cWm[k]*hl + cWp[k]*hr
                  + cCm[k]*hd + cCp[k]*hu + cF[k];
        }
        __syncthreads();               // all reads done before overwrite
        #pragma unroll
        for (int k = 0; k < 8; ++k) {
            int e = t + (k << 10);
            sh[e] = hn[k];
            h0[k] = h[k]; h[k] = hn[k];
        }
        __syncthreads();
    }

    float* op = out + (size_t)rowb * ROW;
    #pragma unroll
    for (int k = 0; k < 8; ++k) {
        int e = t + (k << 10);
        int c = e & 63;
        float s  = bog[c] * rsqrtf(bov[c] + 1e-3f);   // tiny arrays, L1-hot
        float bb = bob[c] - bom[c]*s;
        op[e] = fmaxf(0.f, h[k]*s + bb);
    }
}

// ---------------------------------------------------------------------------
extern "C" void kernel_launch(void* const* d_in, const int* in_sizes, int n_in,
                              void* d_out, int out_size, void* d_ws, size_t ws_size,
                              hipStream_t stream)
{
    const float* x    = (const float*)d_in[0];
    const float* f_w  = (const float*)d_in[1];
    const float* g_w  = (const float*)d_in[2];
    const float* bnf_g = (const float*)d_in[3];
    const float* bnf_b = (const float*)d_in[4];
    const float* bnf_m = (const float*)d_in[5];
    const float* bnf_v = (const float*)d_in[6];
    const float* bng_g = (const float*)d_in[7];
    const float* bng_b = (const float*)d_in[8];
    const float* bng_m = (const float*)d_in[9];
    const float* bng_v = (const float*)d_in[10];
    const float* bno_g = (const float*)d_in[11];
    const float* bno_b = (const float*)d_in[12];
    const float* bno_m = (const float*)d_in[13];
    const float* bno_v = (const float*)d_in[14];

    float* out = (float*)d_out;
    const size_t N = (size_t)16 * HH * WW * CC;   // 16,777,216
    float* buf0 = (float*)d_ws;                   // y1t / y2t  (64 MB)
    float* fbuf = (float*)d_ws + N;               // f          (64 MB)

    // y1t = relu(bn_f(x)) transposed
    bn_relu_transpose<<<2048, 256, 0, stream>>>(x, buf0, bnf_g, bnf_b, bnf_m, bnf_v);
    // f = conv(y1, f_w)
    conv3x3<<<1024, 256, 0, stream>>>(buf0, f_w, fbuf);
    // y2t = relu(bn_g(f)) transposed
    bn_relu_transpose<<<2048, 256, 0, stream>>>(fbuf, buf0, bng_g, bng_b, bng_m, bng_v);
    // g = conv(y2, g_w) -> second output slot
    conv3x3<<<1024, 256, 0, stream>>>(buf0, g_w, out + N);
    // diffusion + bn_o + relu -> first output slot
    diffuse<<<2048, 1024, 0, stream>>>(fbuf, out + N, out, bno_g, bno_b, bno_m, bno_v);
}

// Round 3
// 433.262 us; speedup vs baseline: 1.8623x; 1.8623x over previous
//
#include <hip/hip_runtime.h>

#define HH 128
#define WW 128
#define CC 64
#define ROW (WW*CC)          // 8192 elements per (b,h) row
#define PADW 72              // f16 elements per pixel slot in conv LDS (16B-aligned)

typedef _Float16 half8 __attribute__((ext_vector_type(8)));
typedef _Float16 half4v __attribute__((ext_vector_type(4)));
typedef float floatx4 __attribute__((ext_vector_type(4)));

// ---------------------------------------------------------------------------
// Repack HWIO fp32 weights [3][3][64][64] -> f16 B-frag layout:
// W2[((tap*2+kc)*4+quad)*64 + cout][8] holds W[tap][kc*32+quad*8+j][cout], j=0..7
// so a lane (n=lane&15, quad=lane>>4) reads its 16B B-fragment contiguously.
// ---------------------------------------------------------------------------
__global__ __launch_bounds__(256)
void repack_w(const float* __restrict__ wf, const float* __restrict__ wg,
              _Float16* __restrict__ W2f, _Float16* __restrict__ W2g)
{
    int idx = blockIdx.x * 256 + threadIdx.x;      // 0..73727
    int sel = idx >= 36864;
    int id  = sel ? idx - 36864 : idx;             // (t*64 + c)*64 + o
    const float* src = sel ? wg : wf;
    _Float16* dst = sel ? W2g : W2f;
    int t = id >> 12, c = (id >> 6) & 63, o = id & 63;
    int kc = c >> 5, q = (c >> 3) & 3, j = c & 7;
    int pos = ((((t*2 + kc)*4 + q)*64 + o) << 3) + j;
    dst[pos] = (_Float16)src[id];
}

// ---------------------------------------------------------------------------
// y = relu(bn(x)) cast to f16, elementwise. One thread = 4 elements.
// ---------------------------------------------------------------------------
__global__ __launch_bounds__(256, 8)
void bn_relu_f16(const float* __restrict__ src, _Float16* __restrict__ dst,
                 const float* __restrict__ gma, const float* __restrict__ bta,
                 const float* __restrict__ mu,  const float* __restrict__ var)
{
    __shared__ float sc[CC], bi[CC];
    const int t = threadIdx.x;
    if (t < CC) {
        float s = gma[t] * rsqrtf(var[t] + 1e-3f);
        sc[t] = s; bi[t] = bta[t] - mu[t]*s;
    }
    __syncthreads();
    size_t gid = (size_t)blockIdx.x * 256 + t;     // float4 index
    float4 x = ((const float4*)src)[gid];
    int c = ((int)gid & 15) * 4;
    half4v o;
    o[0] = (_Float16)fmaxf(0.f, x.x*sc[c+0] + bi[c+0]);
    o[1] = (_Float16)fmaxf(0.f, x.y*sc[c+1] + bi[c+1]);
    o[2] = (_Float16)fmaxf(0.f, x.z*sc[c+2] + bi[c+2]);
    o[3] = (_Float16)fmaxf(0.f, x.w*sc[c+3] + bi[c+3]);
    *(half4v*)(dst + gid*4) = o;
}

// ---------------------------------------------------------------------------
// Implicit-GEMM 3x3 SAME conv via f16 MFMA. One block = one (b,i) output row
// (128 px x 64 couts). LDS: rows i-1,i,i+1 with zero pixel slots 0 and 129.
// A-frag: A[m=lane&15 (pixel)][k=quad*8+j (cin)]  -> ds_read_b128
// B-frag: B[k=quad*8+j (cin)][n=lane&15 (cout)]   -> repacked W2 global read
// C/D:    col(lane&15)=cout, row(quad*4+reg)=pixel  [m89-verified]
// Epilogue: optional fp32 store, f16 store, fused relu(bn()) f16 store.
// ---------------------------------------------------------------------------
__global__ __launch_bounds__(256, 2)
void conv_mfma(const _Float16* __restrict__ src, const _Float16* __restrict__ W2,
               _Float16* __restrict__ outH, float* __restrict__ outF,
               _Float16* __restrict__ y2,
               const float* __restrict__ bg, const float* __restrict__ bb,
               const float* __restrict__ bm, const float* __restrict__ bv)
{
    __shared__ _Float16 sIn[3*130*PADW];           // 56160 B -> 2 blocks/CU
    const int t = threadIdx.x;
    const int rowId = blockIdx.x;                  // b*128 + i
    const int b = rowId >> 7, i = rowId & 127;

    // stage 3 input rows (f16 NHWC), zero-filled if out of range
    for (int r = 0; r < 3; ++r) {
        int iy = i + r - 1;
        bool inb = (iy >= 0) && (iy < HH);
        const _Float16* gsrc = src + ((size_t)(b*HH + iy)) * ROW;
        #pragma unroll
        for (int k = 0; k < 4; ++k) {
            int idx = t + k*256;                   // 1024 chunks of 8
            int px = idx >> 3, c8 = (idx & 7) << 3;
            half8 v = {0,0,0,0,0,0,0,0};
            if (inb) v = *(const half8*)(gsrc + px*CC + c8);
            *(half8*)(sIn + (r*130 + px + 1)*PADW + c8) = v;
        }
    }
    // zero edge pixel slots (slot 0 and 129) x 3 rows x 64 c
    if (t < 96) {
        int rr = t >> 5, s = (t >> 4) & 1, c4 = (t & 15) << 2;
        int slot = s ? 129 : 0;
        half4v z = {0,0,0,0};
        *(half4v*)(sIn + (rr*130 + slot)*PADW + c4) = z;
    }
    __syncthreads();

    const int wv = t >> 6, lane = t & 63;
    const int lm = lane & 15, quad = lane >> 4;
    const int p0 = wv * 32;
    floatx4 z4 = {0.f,0.f,0.f,0.f};
    floatx4 acc[2][4];
    #pragma unroll
    for (int ms = 0; ms < 2; ++ms)
        #pragma unroll
        for (int nt = 0; nt < 4; ++nt) acc[ms][nt] = z4;

    #pragma unroll
    for (int tap = 0; tap < 9; ++tap) {
        const int di = tap / 3, dj = tap % 3;
        #pragma unroll
        for (int kc = 0; kc < 2; ++kc) {
            const _Float16* ab = sIn + (di*130 + p0 + lm + dj)*PADW + kc*32 + quad*8;
            half8 a0 = *(const half8*)(ab);
            half8 a1 = *(const half8*)(ab + 16*PADW);
            const _Float16* wb = W2 + (((tap*2 + kc)*4 + quad) << 9) + (lm << 3);
            half8 b0 = *(const half8*)(wb);
            half8 b1 = *(const half8*)(wb + 128);
            half8 b2 = *(const half8*)(wb + 256);
            half8 b3 = *(const half8*)(wb + 384);
            acc[0][0] = __builtin_amdgcn_mfma_f32_16x16x32_f16(a0, b0, acc[0][0], 0,0,0);
            acc[1][0] = __builtin_amdgcn_mfma_f32_16x16x32_f16(a1, b0, acc[1][0], 0,0,0);
            acc[0][1] = __builtin_amdgcn_mfma_f32_16x16x32_f16(a0, b1, acc[0][1], 0,0,0);
            acc[1][1] = __builtin_amdgcn_mfma_f32_16x16x32_f16(a1, b1, acc[1][1], 0,0,0);
            acc[0][2] = __builtin_amdgcn_mfma_f32_16x16x32_f16(a0, b2, acc[0][2], 0,0,0);
            acc[1][2] = __builtin_amdgcn_mfma_f32_16x16x32_f16(a1, b2, acc[1][2], 0,0,0);
            acc[0][3] = __builtin_amdgcn_mfma_f32_16x16x32_f16(a0, b3, acc[0][3], 0,0,0);
            acc[1][3] = __builtin_amdgcn_mfma_f32_16x16x32_f16(a1, b3, acc[1][3], 0,0,0);
        }
    }

    const size_t obase = (size_t)rowId * ROW;
    #pragma unroll
    for (int ms = 0; ms < 2; ++ms) {
        int pix = p0 + ms*16 + quad*4;
        #pragma unroll
        for (int nt = 0; nt < 4; ++nt) {
            int c = nt*16 + lm;
            floatx4 v = acc[ms][nt];
            if (outF) {
                #pragma unroll
                for (int r = 0; r < 4; ++r)
                    outF[obase + (size_t)(pix + r)*CC + c] = v[r];
            }
            if (outH) {
                #pragma unroll
                for (int r = 0; r < 4; ++r)
                    outH[obase + (size_t)(pix + r)*CC + c] = (_Float16)v[r];
            }
            if (y2) {
                float s  = bg[c] * rsqrtf(bv[c] + 1e-3f);
                float bi = bb[c] - bm[c]*s;
                #pragma unroll
                for (int r = 0; r < 4; ++r)
                    y2[obase + (size_t)(pix + r)*CC + c] =
                        (_Float16)fmaxf(0.f, v[r]*s + bi);
            }
        }
    }
}

// ---------------------------------------------------------------------------
// Sobel coefficients + K=5 diffusion + relu(bn_o). One block per (b,h) row.
// f is now f16; g is fp32 (the actual output tensor). Unchanged otherwise.
// ---------------------------------------------------------------------------
__global__ __launch_bounds__(1024, 4)
void diffuse(const _Float16* __restrict__ f, const float* __restrict__ g,
             float* __restrict__ out,
             const float* __restrict__ bog, const float* __restrict__ bob,
             const float* __restrict__ bom, const float* __restrict__ bov)
{
    __shared__ float sA[ROW], sB[ROW];     // 64 KB total -> 2 blocks/CU
    const int t = threadIdx.x;
    const int rowb = blockIdx.x;           // b*128 + i
    const int b = rowb >> 7, i = rowb & 127;
    const int im = (i == 0)    ? 1    : i - 1;   // reflect
    const int ip = (i == HH-1) ? HH-2 : i + 1;
    const _Float16* fb  = f + (size_t)b * (HH*ROW);
    const _Float16* frm = fb + (size_t)im * ROW;
    const _Float16* fr0 = fb + (size_t)i  * ROW;
    const _Float16* frp = fb + (size_t)ip * ROW;
    const float* gr  = g + (size_t)rowb * ROW;

    // stage 1: sA = f[i-1], sB = f[i+1]   (8 f16 per thread)
    {
        int o = t * 8;
        half8 va = *(const half8*)(frm + o);
        half8 vb = *(const half8*)(frp + o);
        #pragma unroll
        for (int j = 0; j < 8; ++j) { sA[o+j] = (float)va[j]; sB[o+j] = (float)vb[j]; }
    }
    __syncthreads();

    float dy8[8], dxp8[8];
    #pragma unroll
    for (int k = 0; k < 8; ++k) {
        int e = t + (k << 10);
        int w = e >> 6, c = e & 63;
        int wm  = (w == 0)    ? 1    : w - 1;
        int wpp = (w == WW-1) ? WW-2 : w + 1;
        float amm = sA[wm*CC+c], am0 = sA[w*CC+c], amp = sA[wpp*CC+c];
        float bmm = sB[wm*CC+c], bm0 = sB[w*CC+c], bmp = sB[wpp*CC+c];
        dy8[k]  = (bmm + 2.f*bm0 + bmp) - (amm + 2.f*am0 + amp);
        dxp8[k] = (amp - amm) + (bmp - bmm);
    }
    __syncthreads();

    // stage 2: sA = f[i] (becomes h), sB = g[i]
    {
        int o = t * 8;
        half8 va = *(const half8*)(fr0 + o);
        #pragma unroll
        for (int j = 0; j < 8; ++j) sA[o+j] = (float)va[j];
        int o4 = t * 4;
        *(float4*)(sB + o4)        = *(const float4*)(gr + o4);
        *(float4*)(sB + o4 + 4096) = *(const float4*)(gr + o4 + 4096);
    }
    __syncthreads();

    float cH0[8], cEE[8], cWm[8], cWp[8], cCm[8], cCp[8], cF[8], h0[8], h[8];
    #pragma unroll
    for (int k = 0; k < 8; ++k) {
        int e = t + (k << 10);
        int w = e >> 6, c = e & 63;
        int wm  = (w == 0)    ? 1    : w - 1;
        int wpp = (w == WW-1) ? WW-2 : w + 1;
        float fwm = sA[wm*CC+c], fv = sA[w*CC+c], fwp = sA[wpp*CC+c];
        float dx = dxp8[k] + 2.f*(fwp - fwm);
        float dy = dy8[k];
        float Bx = 0.2f / (dy*dy*0.25f + 1.f);
        float By = 0.2f / (dx*dx*0.25f + 1.f);
        float gv = sB[w*CC+c];
        float A  = gv * 0.2f;
        float gl  = sB[((w+WW-1)&(WW-1))*CC + c];
        float grr = sB[((w+1)   &(WW-1))*CC + c];
        float gd  = sB[w*CC + ((c+CC-1)&(CC-1))];
        float gu  = sB[w*CC + ((c+1)   &(CC-1))];
        float E  = ((gl - grr) + (gd - gu)) * 0.5f * 0.2f;
        float Dd = 1.f / (1.f + 2.f*Bx + 2.f*By);
        cH0[k] = Dd * (1.f - 2.f*Bx - 2.f*By);
        cEE[k] = -2.f * E * Dd;
        cWm[k] = Dd * (2.f*Bx - A);
        cWp[k] = Dd * (2.f*Bx + A);
        cCm[k] = Dd * (2.f*By - A);
        cCp[k] = Dd * (2.f*By + A);
        cF[k]  = Dd * 0.4f * fv;
        h0[k] = fv; h[k] = fv;
    }

    float* sh = sA;
    for (int it = 0; it < 5; ++it) {
        float hn[8];
        #pragma unroll
        for (int k = 0; k < 8; ++k) {
            int e = t + (k << 10);
            int w = e >> 6, c = e & 63;
            float hl = sh[((w+WW-1)&(WW-1))*CC + c];
            float hr = sh[((w+1)   &(WW-1))*CC + c];
            float hd = sh[w*CC + ((c+CC-1)&(CC-1))];
            float hu = sh[w*CC + ((c+1)   &(CC-1))];
            hn[k] = cH0[k]*h0[k] + cEE[k]*h[k] + cWm[k]*hl + cWp[k]*hr
                  + cCm[k]*hd + cCp[k]*hu + cF[k];
        }
        __syncthreads();
        #pragma unroll
        for (int k = 0; k < 8; ++k) {
            int e = t + (k << 10);
            sh[e] = hn[k];
            h0[k] = h[k]; h[k] = hn[k];
        }
        __syncthreads();
    }

    float* op = out + (size_t)rowb * ROW;
    #pragma unroll
    for (int k = 0; k < 8; ++k) {
        int e = t + (k << 10);
        int c = e & 63;
        float s  = bog[c] * rsqrtf(bov[c] + 1e-3f);
        float bb = bob[c] - bom[c]*s;
        op[e] = fmaxf(0.f, h[k]*s + bb);
    }
}

// ---------------------------------------------------------------------------
extern "C" void kernel_launch(void* const* d_in, const int* in_sizes, int n_in,
                              void* d_out, int out_size, void* d_ws, size_t ws_size,
                              hipStream_t stream)
{
    const float* x    = (const float*)d_in[0];
    const float* f_w  = (const float*)d_in[1];
    const float* g_w  = (const float*)d_in[2];
    const float* bnf_g = (const float*)d_in[3];
    const float* bnf_b = (const float*)d_in[4];
    const float* bnf_m = (const float*)d_in[5];
    const float* bnf_v = (const float*)d_in[6];
    const float* bng_g = (const float*)d_in[7];
    const float* bng_b = (const float*)d_in[8];
    const float* bng_m = (const float*)d_in[9];
    const float* bng_v = (const float*)d_in[10];
    const float* bno_g = (const float*)d_in[11];
    const float* bno_b = (const float*)d_in[12];
    const float* bno_m = (const float*)d_in[13];
    const float* bno_v = (const float*)d_in[14];

    float* out = (float*)d_out;
    const size_t N = (size_t)16 * HH * WW * CC;   // 16,777,216
    _Float16* y1  = (_Float16*)d_ws;              // N halfs (32 MB)
    _Float16* y2  = y1 + N;                       // N halfs
    _Float16* fbuf = y1 + 2*N;                    // N halfs
    _Float16* W2f = y1 + 3*N;                     // 36864 halfs
    _Float16* W2g = W2f + 36864;

    // repack both weight tensors into B-frag layout
    repack_w<<<288, 256, 0, stream>>>(f_w, g_w, W2f, W2g);
    // y1 = relu(bn_f(x)) as f16
    bn_relu_f16<<<16384, 256, 0, stream>>>(x, y1, bnf_g, bnf_b, bnf_m, bnf_v);
    // f = conv(y1, f_w): write f16 f AND fused y2 = relu(bn_g(f)) f16
    conv_mfma<<<2048, 256, 0, stream>>>(y1, W2f, fbuf, nullptr, y2,
                                        bng_g, bng_b, bng_m, bng_v);
    // g = conv(y2, g_w): write fp32 straight to output slot 1
    conv_mfma<<<2048, 256, 0, stream>>>(y2, W2g, nullptr, out + N, nullptr,
                                        nullptr, nullptr, nullptr, nullptr);
    // diffusion + bn_o + relu -> output slot 0
    diffuse<<<2048, 1024, 0, stream>>>(fbuf, out + N, out, bno_g, bno_b, bno_m, bno_v);
}

// Round 4
// 409.291 us; speedup vs baseline: 1.9714x; 1.0586x over previous
//
#include <hip/hip_runtime.h>

#define HH 128
#define WW 128
#define CC 64
#define ROW (WW*CC)          // 8192 elements per (b,h) row
#define PADW 72              // f16 elements per pixel slot in conv LDS (16B-aligned)

typedef _Float16 half8 __attribute__((ext_vector_type(8)));
typedef _Float16 half4v __attribute__((ext_vector_type(4)));
typedef float floatx4 __attribute__((ext_vector_type(4)));

// ---------------------------------------------------------------------------
// Repack HWIO fp32 weights [3][3][64][64] -> f16 B-frag layout:
// W2[((tap*2+kc)*4+quad)*64 + cout][8] holds W[tap][kc*32+quad*8+j][cout], j=0..7
// ---------------------------------------------------------------------------
__global__ __launch_bounds__(256)
void repack_w(const float* __restrict__ wf, const float* __restrict__ wg,
              _Float16* __restrict__ W2f, _Float16* __restrict__ W2g)
{
    int idx = blockIdx.x * 256 + threadIdx.x;      // 0..73727
    int sel = idx >= 36864;
    int id  = sel ? idx - 36864 : idx;             // (t*64 + c)*64 + o
    const float* src = sel ? wg : wf;
    _Float16* dst = sel ? W2g : W2f;
    int t = id >> 12, c = (id >> 6) & 63, o = id & 63;
    int kc = c >> 5, q = (c >> 3) & 3, j = c & 7;
    int pos = ((((t*2 + kc)*4 + q)*64 + o) << 3) + j;
    dst[pos] = (_Float16)src[id];
}

// ---------------------------------------------------------------------------
// y = relu(bn(x)) cast to f16, elementwise. One thread = 4 elements.
// ---------------------------------------------------------------------------
__global__ __launch_bounds__(256, 8)
void bn_relu_f16(const float* __restrict__ src, _Float16* __restrict__ dst,
                 const float* __restrict__ gma, const float* __restrict__ bta,
                 const float* __restrict__ mu,  const float* __restrict__ var)
{
    __shared__ float sc[CC], bi[CC];
    const int t = threadIdx.x;
    if (t < CC) {
        float s = gma[t] * rsqrtf(var[t] + 1e-3f);
        sc[t] = s; bi[t] = bta[t] - mu[t]*s;
    }
    __syncthreads();
    size_t gid = (size_t)blockIdx.x * 256 + t;     // float4 index
    float4 x = ((const float4*)src)[gid];
    int c = ((int)gid & 15) * 4;
    half4v o;
    o[0] = (_Float16)fmaxf(0.f, x.x*sc[c+0] + bi[c+0]);
    o[1] = (_Float16)fmaxf(0.f, x.y*sc[c+1] + bi[c+1]);
    o[2] = (_Float16)fmaxf(0.f, x.z*sc[c+2] + bi[c+2]);
    o[3] = (_Float16)fmaxf(0.f, x.w*sc[c+3] + bi[c+3]);
    *(half4v*)(dst + gid*4) = o;
}

// ---------------------------------------------------------------------------
// Implicit-GEMM 3x3 SAME conv via f16 MFMA. One block = one (b,i) output row.
// (unchanged from R3 — correct, not yet the top dispatch)
// ---------------------------------------------------------------------------
__global__ __launch_bounds__(256, 2)
void conv_mfma(const _Float16* __restrict__ src, const _Float16* __restrict__ W2,
               _Float16* __restrict__ outH, float* __restrict__ outF,
               _Float16* __restrict__ y2,
               const float* __restrict__ bg, const float* __restrict__ bb,
               const float* __restrict__ bm, const float* __restrict__ bv)
{
    __shared__ _Float16 sIn[3*130*PADW];           // 56160 B -> 2 blocks/CU
    const int t = threadIdx.x;
    const int rowId = blockIdx.x;                  // b*128 + i
    const int b = rowId >> 7, i = rowId & 127;

    for (int r = 0; r < 3; ++r) {
        int iy = i + r - 1;
        bool inb = (iy >= 0) && (iy < HH);
        const _Float16* gsrc = src + ((size_t)(b*HH + iy)) * ROW;
        #pragma unroll
        for (int k = 0; k < 4; ++k) {
            int idx = t + k*256;                   // 1024 chunks of 8
            int px = idx >> 3, c8 = (idx & 7) << 3;
            half8 v = {0,0,0,0,0,0,0,0};
            if (inb) v = *(const half8*)(gsrc + px*CC + c8);
            *(half8*)(sIn + (r*130 + px + 1)*PADW + c8) = v;
        }
    }
    if (t < 96) {
        int rr = t >> 5, s = (t >> 4) & 1, c4 = (t & 15) << 2;
        int slot = s ? 129 : 0;
        half4v z = {0,0,0,0};
        *(half4v*)(sIn + (rr*130 + slot)*PADW + c4) = z;
    }
    __syncthreads();

    const int wv = t >> 6, lane = t & 63;
    const int lm = lane & 15, quad = lane >> 4;
    const int p0 = wv * 32;
    floatx4 z4 = {0.f,0.f,0.f,0.f};
    floatx4 acc[2][4];
    #pragma unroll
    for (int ms = 0; ms < 2; ++ms)
        #pragma unroll
        for (int nt = 0; nt < 4; ++nt) acc[ms][nt] = z4;

    #pragma unroll
    for (int tap = 0; tap < 9; ++tap) {
        const int di = tap / 3, dj = tap % 3;
        #pragma unroll
        for (int kc = 0; kc < 2; ++kc) {
            const _Float16* ab = sIn + (di*130 + p0 + lm + dj)*PADW + kc*32 + quad*8;
            half8 a0 = *(const half8*)(ab);
            half8 a1 = *(const half8*)(ab + 16*PADW);
            const _Float16* wb = W2 + (((tap*2 + kc)*4 + quad) << 9) + (lm << 3);
            half8 b0 = *(const half8*)(wb);
            half8 b1 = *(const half8*)(wb + 128);
            half8 b2 = *(const half8*)(wb + 256);
            half8 b3 = *(const half8*)(wb + 384);
            acc[0][0] = __builtin_amdgcn_mfma_f32_16x16x32_f16(a0, b0, acc[0][0], 0,0,0);
            acc[1][0] = __builtin_amdgcn_mfma_f32_16x16x32_f16(a1, b0, acc[1][0], 0,0,0);
            acc[0][1] = __builtin_amdgcn_mfma_f32_16x16x32_f16(a0, b1, acc[0][1], 0,0,0);
            acc[1][1] = __builtin_amdgcn_mfma_f32_16x16x32_f16(a1, b1, acc[1][1], 0,0,0);
            acc[0][2] = __builtin_amdgcn_mfma_f32_16x16x32_f16(a0, b2, acc[0][2], 0,0,0);
            acc[1][2] = __builtin_amdgcn_mfma_f32_16x16x32_f16(a1, b2, acc[1][2], 0,0,0);
            acc[0][3] = __builtin_amdgcn_mfma_f32_16x16x32_f16(a0, b3, acc[0][3], 0,0,0);
            acc[1][3] = __builtin_amdgcn_mfma_f32_16x16x32_f16(a1, b3, acc[1][3], 0,0,0);
        }
    }

    const size_t obase = (size_t)rowId * ROW;
    #pragma unroll
    for (int ms = 0; ms < 2; ++ms) {
        int pix = p0 + ms*16 + quad*4;
        #pragma unroll
        for (int nt = 0; nt < 4; ++nt) {
            int c = nt*16 + lm;
            floatx4 v = acc[ms][nt];
            if (outF) {
                #pragma unroll
                for (int r = 0; r < 4; ++r)
                    outF[obase + (size_t)(pix + r)*CC + c] = v[r];
            }
            if (outH) {
                #pragma unroll
                for (int r = 0; r < 4; ++r)
                    outH[obase + (size_t)(pix + r)*CC + c] = (_Float16)v[r];
            }
            if (y2) {
                float s  = bg[c] * rsqrtf(bv[c] + 1e-3f);
                float bi = bb[c] - bm[c]*s;
                #pragma unroll
                for (int r = 0; r < 4; ++r)
                    y2[obase + (size_t)(pix + r)*CC + c] =
                        (_Float16)fmaxf(0.f, v[r]*s + bi);
            }
        }
    }
}

// ---------------------------------------------------------------------------
// Sobel + K=5 diffusion + relu(bn_o). One block per (b,h) row, 1024 thr.
// R4 redesign: thread t owns float4 chunks at e=4t and 4t+4096 ->
//  - all LDS ops are lane-contiguous b128 (conflict-free) + 4 edge b32/iter
//  - coeffs folded to 6 float4s per chunk (P,R,Q,cH0,cEE,cF), h/h0 in regs
//  - LDS addresses loop-invariant; h ping-pongs B0<->B1 (1 barrier/iter)
// ---------------------------------------------------------------------------
__global__ __launch_bounds__(1024, 4)
void diffuse(const _Float16* __restrict__ f, const float* __restrict__ g,
             float* __restrict__ out,
             const float* __restrict__ bog, const float* __restrict__ bob,
             const float* __restrict__ bom, const float* __restrict__ bov)
{
    __shared__ float B0[ROW], B1[ROW];     // 2 x 32 KB
    const int t = threadIdx.x;
    const int rowb = blockIdx.x;           // b*128 + i
    const int b = rowb >> 7, i = rowb & 127;
    const int im = (i == 0)    ? 1    : i - 1;   // reflect
    const int ip = (i == HH-1) ? HH-2 : i + 1;
    const _Float16* fb  = f + (size_t)b * (HH*ROW);
    const _Float16* frm = fb + (size_t)im * ROW;
    const _Float16* fr0 = fb + (size_t)i  * ROW;
    const _Float16* frp = fb + (size_t)ip * ROW;
    const float* grow = g + (size_t)rowb * ROW;

    const int w0 = t >> 4, c0 = (t & 15) << 2;
    const int qch[2] = { t*4, t*4 + 4096 };        // == w*64 + c0
    const int wch[2] = { w0, w0 + 64 };

    // ---- stage f[i-1]->B0, f[i+1]->B1 (f16 -> f32, b128 stores)
    #pragma unroll
    for (int k = 0; k < 2; ++k) {
        half4v vm = *(const half4v*)(frm + qch[k]);
        half4v vp = *(const half4v*)(frp + qch[k]);
        floatx4 a = { (float)vm[0], (float)vm[1], (float)vm[2], (float)vm[3] };
        floatx4 p = { (float)vp[0], (float)vp[1], (float)vp[2], (float)vp[3] };
        *(floatx4*)(B0 + qch[k]) = a;
        *(floatx4*)(B1 + qch[k]) = p;
    }
    __syncthreads();

    // ---- Sobel partials from rows i+-1 (REFLECT in W)
    floatx4 Bx4[2], dxp4[2];
    #pragma unroll
    for (int k = 0; k < 2; ++k) {
        int w = wch[k];
        int wm = (w == 0)    ? 1      : w - 1;
        int wp = (w == WW-1) ? WW - 2 : w + 1;
        floatx4 am = *(const floatx4*)(B0 + wm*CC + c0);
        floatx4 a0 = *(const floatx4*)(B0 + w *CC + c0);
        floatx4 ap = *(const floatx4*)(B0 + wp*CC + c0);
        floatx4 bm = *(const floatx4*)(B1 + wm*CC + c0);
        floatx4 b0 = *(const floatx4*)(B1 + w *CC + c0);
        floatx4 bp = *(const floatx4*)(B1 + wp*CC + c0);
        floatx4 dy = (bm + 2.f*b0 + bp) - (am + 2.f*a0 + ap);
        Bx4[k]  = 0.2f / (dy*dy*0.25f + 1.f);      // Dx*DT
        dxp4[k] = (ap - am) + (bp - bm);
    }
    __syncthreads();                               // reads done before restage

    // ---- stage f[i]->B0 (= h_0), g->B1
    #pragma unroll
    for (int k = 0; k < 2; ++k) {
        half4v v0 = *(const half4v*)(fr0 + qch[k]);
        floatx4 fv = { (float)v0[0], (float)v0[1], (float)v0[2], (float)v0[3] };
        *(floatx4*)(B0 + qch[k]) = fv;
        *(floatx4*)(B1 + qch[k]) = *(const floatx4*)(grow + qch[k]);
    }
    __syncthreads();

    // ---- coefficients (all loop-state in registers as float4)
    floatx4 P4[2], R4[2], Q4[2], cH0[2], cEE[2], cF[2], h4[2], h04[2];
    #pragma unroll
    for (int k = 0; k < 2; ++k) {
        int w = wch[k];
        int wm = (w == 0)    ? 1      : w - 1;     // reflect (sobel dx)
        int wp = (w == WW-1) ? WW - 2 : w + 1;
        int wl = (w + WW - 1) & (WW - 1);          // cyclic (rolls)
        int wr = (w + 1) & (WW - 1);
        floatx4 fm = *(const floatx4*)(B0 + wm*CC + c0);
        floatx4 fv = *(const floatx4*)(B0 + w *CC + c0);
        floatx4 fp = *(const floatx4*)(B0 + wp*CC + c0);
        floatx4 dx = dxp4[k] + 2.f*(fp - fm);
        floatx4 By = 0.2f / (dx*dx*0.25f + 1.f);   // Dy*DT
        floatx4 Bx = Bx4[k];
        floatx4 gv = *(const floatx4*)(B1 + w *CC + c0);
        floatx4 gl = *(const floatx4*)(B1 + wl*CC + c0);
        floatx4 gr = *(const floatx4*)(B1 + wr*CC + c0);
        float gdm = B1[w*CC + ((c0 + 63) & 63)];
        float gup = B1[w*CC + ((c0 + 4) & 63)];
        floatx4 gd = { gdm, gv[0], gv[1], gv[2] }; // g[c-1] cyclic
        floatx4 gu = { gv[1], gv[2], gv[3], gup }; // g[c+1] cyclic
        floatx4 E  = ((gl - gr) + (gd - gu)) * 0.1f;     // (ux+vy)*DT
        floatx4 A  = gv * 0.2f;                          // g*DT
        floatx4 Dd = 1.f / (1.f + 2.f*Bx + 2.f*By);
        cH0[k] = 2.f*Dd - 1.f;            // == Dd*(1-2Bx-2By)
        cEE[k] = -2.f * E * Dd;
        P4[k]  = 2.f * Bx * Dd;
        R4[k]  = 2.f * By * Dd;
        Q4[k]  = A * Dd;
        cF[k]  = 0.4f * Dd * fv;          // Dd * 2*DT*f
        h4[k] = fv; h04[k] = fv;
    }
    __syncthreads();                               // g reads done before loop writes B1

    // loop-invariant LDS offsets
    int oWl[2], oWr[2], oDm[2], oDu[2];
    #pragma unroll
    for (int k = 0; k < 2; ++k) {
        int w = wch[k];
        oWl[k] = ((w + WW - 1) & (WW - 1))*CC + c0;
        oWr[k] = ((w + 1) & (WW - 1))*CC + c0;
        oDm[k] = w*CC + ((c0 + 63) & 63);
        oDu[k] = w*CC + ((c0 + 4) & 63);
    }

    // ---- K=5 diffusion, h ping-pong B0 -> B1 -> B0 ...
    float* cur = B0;
    float* oth = B1;
    for (int it = 0; it < 5; ++it) {
        #pragma unroll
        for (int k = 0; k < 2; ++k) {
            floatx4 hl = *(const floatx4*)(cur + oWl[k]);
            floatx4 hr = *(const floatx4*)(cur + oWr[k]);
            float hdm = cur[oDm[k]];
            float hup = cur[oDu[k]];
            floatx4 hv = h4[k];
            floatx4 hd = { hdm, hv[0], hv[1], hv[2] };
            floatx4 hu = { hv[1], hv[2], hv[3], hup };
            floatx4 hn = cH0[k]*h04[k] + cEE[k]*hv
                       + P4[k]*(hl + hr) + R4[k]*(hd + hu)
                       + Q4[k]*((hr - hl) + (hu - hd)) + cF[k];
            *(floatx4*)(oth + qch[k]) = hn;
            h04[k] = hv; h4[k] = hn;
        }
        __syncthreads();
        float* tmp = cur; cur = oth; oth = tmp;
    }

    // ---- epilogue: relu(bn_o(h)) from registers, float4 stores
    floatx4 gg = *(const floatx4*)(bog + c0);
    floatx4 vv = *(const floatx4*)(bov + c0);
    floatx4 bb = *(const floatx4*)(bob + c0);
    floatx4 mm = *(const floatx4*)(bom + c0);
    floatx4 s4, bi4;
    #pragma unroll
    for (int j = 0; j < 4; ++j) s4[j] = gg[j] * rsqrtf(vv[j] + 1e-3f);
    bi4 = bb - mm*s4;
    float* op = out + (size_t)rowb * ROW;
    #pragma unroll
    for (int k = 0; k < 2; ++k) {
        floatx4 r = h4[k]*s4 + bi4;
        #pragma unroll
        for (int j = 0; j < 4; ++j) r[j] = fmaxf(0.f, r[j]);
        *(floatx4*)(op + qch[k]) = r;
    }
}

// ---------------------------------------------------------------------------
extern "C" void kernel_launch(void* const* d_in, const int* in_sizes, int n_in,
                              void* d_out, int out_size, void* d_ws, size_t ws_size,
                              hipStream_t stream)
{
    const float* x    = (const float*)d_in[0];
    const float* f_w  = (const float*)d_in[1];
    const float* g_w  = (const float*)d_in[2];
    const float* bnf_g = (const float*)d_in[3];
    const float* bnf_b = (const float*)d_in[4];
    const float* bnf_m = (const float*)d_in[5];
    const float* bnf_v = (const float*)d_in[6];
    const float* bng_g = (const float*)d_in[7];
    const float* bng_b = (const float*)d_in[8];
    const float* bng_m = (const float*)d_in[9];
    const float* bng_v = (const float*)d_in[10];
    const float* bno_g = (const float*)d_in[11];
    const float* bno_b = (const float*)d_in[12];
    const float* bno_m = (const float*)d_in[13];
    const float* bno_v = (const float*)d_in[14];

    float* out = (float*)d_out;
    const size_t N = (size_t)16 * HH * WW * CC;   // 16,777,216
    _Float16* y1  = (_Float16*)d_ws;              // N halfs (32 MB)
    _Float16* y2  = y1 + N;                       // N halfs
    _Float16* fbuf = y1 + 2*N;                    // N halfs
    _Float16* W2f = y1 + 3*N;                     // 36864 halfs
    _Float16* W2g = W2f + 36864;

    repack_w<<<288, 256, 0, stream>>>(f_w, g_w, W2f, W2g);
    bn_relu_f16<<<16384, 256, 0, stream>>>(x, y1, bnf_g, bnf_b, bnf_m, bnf_v);
    conv_mfma<<<2048, 256, 0, stream>>>(y1, W2f, fbuf, nullptr, y2,
                                        bng_g, bng_b, bng_m, bng_v);
    conv_mfma<<<2048, 256, 0, stream>>>(y2, W2g, nullptr, out + N, nullptr,
                                        nullptr, nullptr, nullptr, nullptr);
    diffuse<<<2048, 1024, 0, stream>>>(fbuf, out + N, out, bno_g, bno_b, bno_m, bno_v);
}

// Round 5
// 376.820 us; speedup vs baseline: 2.1413x; 1.0862x over previous
//
#include <hip/hip_runtime.h>

#define HH 128
#define WW 128
#define CC 64
#define ROW (WW*CC)          // 8192 elements per (b,h) row
#define PADW 72              // f16 elems per pixel slot in conv LDS (byte stride 144 = 16*9)

typedef _Float16 half8 __attribute__((ext_vector_type(8)));
typedef _Float16 half4v __attribute__((ext_vector_type(4)));
typedef float floatx4 __attribute__((ext_vector_type(4)));

// ---------------------------------------------------------------------------
// Repack HWIO fp32 weights [3][3][64][64] -> f16 B-frag layout:
// W2[(step*4+q)*512 + o*8 + j] = W[tap][kc*32+q*8+j][o], step = tap*2+kc
// ---------------------------------------------------------------------------
__global__ __launch_bounds__(256)
void repack_w(const float* __restrict__ wf, const float* __restrict__ wg,
              _Float16* __restrict__ W2f, _Float16* __restrict__ W2g)
{
    int idx = blockIdx.x * 256 + threadIdx.x;      // 0..73727
    int sel = idx >= 36864;
    int id  = sel ? idx - 36864 : idx;             // (t*64 + c)*64 + o
    const float* src = sel ? wg : wf;
    _Float16* dst = sel ? W2g : W2f;
    int t = id >> 12, c = (id >> 6) & 63, o = id & 63;
    int kc = c >> 5, q = (c >> 3) & 3, j = c & 7;
    int pos = ((((t*2 + kc)*4 + q)*64 + o) << 3) + j;
    dst[pos] = (_Float16)src[id];
}

// ---------------------------------------------------------------------------
// Implicit-GEMM 3x3 SAME conv via f16 MFMA.
// Block = 2 output rows (b, i0..i0+1). LDS: 4 input rows (i0-1..i0+2),
// 130 pixel slots (0 and 129 zero), PADW stride. Wave = 64 px x 64 couts:
// acc[4][4], 16 MFMAs per 4 B-frag loads (2x reuse vs R4).
// BNIN=1: src is fp32 x, staging applies relu(bn_f) and casts f16.
// EPI=1:  writes f16 outH and fused y2 = relu(bn_g(acc)) f16.
// EPI=0:  writes fp32 outF.
// A-frag A[m=lane&15][k=quad*8+j] via ds_read_b128; B-frag from repacked W2.
// C/D: col(lane&15)=cout, row(quad*4+reg)=pixel  [m89-verified, R3/R4-proven]
// ---------------------------------------------------------------------------
template<int BNIN, int EPI>
__global__ __launch_bounds__(256, 2)
void conv_mfma(const void* __restrict__ srcv, const _Float16* __restrict__ W2,
               _Float16* __restrict__ outH, float* __restrict__ outF,
               _Float16* __restrict__ y2,
               const float* __restrict__ ig, const float* __restrict__ ib,
               const float* __restrict__ imu, const float* __restrict__ iva,
               const float* __restrict__ og, const float* __restrict__ ob,
               const float* __restrict__ om, const float* __restrict__ ov)
{
    __shared__ _Float16 sIn[4*130*PADW];           // 74880 B -> 2 blocks/CU
    const int t = threadIdx.x;
    const int blk = blockIdx.x;                    // b*64 + ipair
    const int b = blk >> 6, i0 = (blk & 63) * 2;

    // per-thread BN constants for staging (c8 = (t&7)*8 is k-invariant)
    const int c8 = (t & 7) << 3;
    float scv[8], biv[8];
    if (BNIN) {
        #pragma unroll
        for (int j = 0; j < 8; ++j) {
            float s = ig[c8+j] * rsqrtf(iva[c8+j] + 1e-3f);
            scv[j] = s; biv[j] = ib[c8+j] - imu[c8+j]*s;
        }
    }

    // stage 4 input rows (i0-1 .. i0+2)
    for (int r = 0; r < 4; ++r) {
        int iy = i0 - 1 + r;
        bool inb = (iy >= 0) && (iy < HH);
        #pragma unroll
        for (int k = 0; k < 4; ++k) {
            int idx = t + (k << 8);
            int px = idx >> 3;
            half8 v = {0,0,0,0,0,0,0,0};
            if (inb) {
                if (BNIN) {
                    const float* gp = (const float*)srcv
                        + ((size_t)(b*HH + iy))*ROW + px*CC + c8;
                    float4 u0 = *(const float4*)gp;
                    float4 u1 = *(const float4*)(gp + 4);
                    v[0] = (_Float16)fmaxf(0.f, u0.x*scv[0] + biv[0]);
                    v[1] = (_Float16)fmaxf(0.f, u0.y*scv[1] + biv[1]);
                    v[2] = (_Float16)fmaxf(0.f, u0.z*scv[2] + biv[2]);
                    v[3] = (_Float16)fmaxf(0.f, u0.w*scv[3] + biv[3]);
                    v[4] = (_Float16)fmaxf(0.f, u1.x*scv[4] + biv[4]);
                    v[5] = (_Float16)fmaxf(0.f, u1.y*scv[5] + biv[5]);
                    v[6] = (_Float16)fmaxf(0.f, u1.z*scv[6] + biv[6]);
                    v[7] = (_Float16)fmaxf(0.f, u1.w*scv[7] + biv[7]);
                } else {
                    v = *(const half8*)((const _Float16*)srcv
                        + ((size_t)(b*HH + iy))*ROW + px*CC + c8);
                }
            }
            *(half8*)(sIn + (r*130 + px + 1)*PADW + c8) = v;
        }
    }
    // zero edge pixel slots (0 and 129) x 4 rows
    if (t < 128) {
        int rr = t >> 5, s = (t >> 4) & 1, c4 = (t & 15) << 2;
        int slot = s ? 129 : 0;
        half4v z = {0,0,0,0};
        *(half4v*)(sIn + (rr*130 + slot)*PADW + c4) = z;
    }
    __syncthreads();

    const int wv = t >> 6, lane = t & 63;
    const int lm = lane & 15, quad = lane >> 4;
    const int r  = wv >> 1;                        // local output row 0/1
    const int px0 = (wv & 1) * 64;
    floatx4 z4 = {0.f,0.f,0.f,0.f};
    floatx4 acc[4][4];
    #pragma unroll
    for (int ms = 0; ms < 4; ++ms)
        #pragma unroll
        for (int nt = 0; nt < 4; ++nt) acc[ms][nt] = z4;

    #pragma unroll
    for (int tap = 0; tap < 9; ++tap) {
        const int di = tap / 3, dj = tap % 3;
        #pragma unroll
        for (int kc = 0; kc < 2; ++kc) {
            const _Float16* ab = sIn + ((r + di)*130 + px0 + lm + dj)*PADW
                               + kc*32 + quad*8;
            half8 a0 = *(const half8*)(ab);
            half8 a1 = *(const half8*)(ab + 16*PADW);
            half8 a2 = *(const half8*)(ab + 32*PADW);
            half8 a3 = *(const half8*)(ab + 48*PADW);
            const _Float16* wb = W2 + (((tap*2 + kc)*4 + quad) << 9) + (lm << 3);
            half8 b0 = *(const half8*)(wb);
            half8 b1 = *(const half8*)(wb + 128);
            half8 b2 = *(const half8*)(wb + 256);
            half8 b3 = *(const half8*)(wb + 384);
            acc[0][0] = __builtin_amdgcn_mfma_f32_16x16x32_f16(a0, b0, acc[0][0], 0,0,0);
            acc[1][0] = __builtin_amdgcn_mfma_f32_16x16x32_f16(a1, b0, acc[1][0], 0,0,0);
            acc[2][0] = __builtin_amdgcn_mfma_f32_16x16x32_f16(a2, b0, acc[2][0], 0,0,0);
            acc[3][0] = __builtin_amdgcn_mfma_f32_16x16x32_f16(a3, b0, acc[3][0], 0,0,0);
            acc[0][1] = __builtin_amdgcn_mfma_f32_16x16x32_f16(a0, b1, acc[0][1], 0,0,0);
            acc[1][1] = __builtin_amdgcn_mfma_f32_16x16x32_f16(a1, b1, acc[1][1], 0,0,0);
            acc[2][1] = __builtin_amdgcn_mfma_f32_16x16x32_f16(a2, b1, acc[2][1], 0,0,0);
            acc[3][1] = __builtin_amdgcn_mfma_f32_16x16x32_f16(a3, b1, acc[3][1], 0,0,0);
            acc[0][2] = __builtin_amdgcn_mfma_f32_16x16x32_f16(a0, b2, acc[0][2], 0,0,0);
            acc[1][2] = __builtin_amdgcn_mfma_f32_16x16x32_f16(a1, b2, acc[1][2], 0,0,0);
            acc[2][2] = __builtin_amdgcn_mfma_f32_16x16x32_f16(a2, b2, acc[2][2], 0,0,0);
            acc[3][2] = __builtin_amdgcn_mfma_f32_16x16x32_f16(a3, b2, acc[3][2], 0,0,0);
            acc[0][3] = __builtin_amdgcn_mfma_f32_16x16x32_f16(a0, b3, acc[0][3], 0,0,0);
            acc[1][3] = __builtin_amdgcn_mfma_f32_16x16x32_f16(a1, b3, acc[1][3], 0,0,0);
            acc[2][3] = __builtin_amdgcn_mfma_f32_16x16x32_f16(a2, b3, acc[2][3], 0,0,0);
            acc[3][3] = __builtin_amdgcn_mfma_f32_16x16x32_f16(a3, b3, acc[3][3], 0,0,0);
        }
    }

    const size_t obase = ((size_t)(b*HH + i0 + r)) * ROW;
    #pragma unroll
    for (int nt = 0; nt < 4; ++nt) {
        int c = nt*16 + lm;
        float s = 0.f, bi2 = 0.f;
        if (EPI) {
            s = og[c] * rsqrtf(ov[c] + 1e-3f);
            bi2 = ob[c] - om[c]*s;
        }
        #pragma unroll
        for (int ms = 0; ms < 4; ++ms) {
            int pix = px0 + ms*16 + quad*4;
            floatx4 v = acc[ms][nt];
            #pragma unroll
            for (int rv = 0; rv < 4; ++rv) {
                size_t o = obase + (size_t)(pix + rv)*CC + c;
                if (EPI) {
                    outH[o] = (_Float16)v[rv];
                    y2[o]   = (_Float16)fmaxf(0.f, v[rv]*s + bi2);
                } else {
                    outF[o] = v[rv];
                }
            }
        }
    }
}

// ---------------------------------------------------------------------------
// Sobel + K=5 diffusion + relu(bn_o). One block per (b,h) row, 1024 thr.
// R5: __launch_bounds__(1024,2) so the ~100-float per-thread state fits in
// VGPRs (R4's (1024,4) capped VGPR at 64 -> scratch spills, 32MB WRITE).
// C-direction cyclic neighbors come from adjacent lanes via __shfl (the
// 16-lane group spans the full 64-channel ring) -> no 8-way-conflict b32 reads.
// ---------------------------------------------------------------------------
__global__ __launch_bounds__(1024, 2)
void diffuse(const _Float16* __restrict__ f, const float* __restrict__ g,
             float* __restrict__ out,
             const float* __restrict__ bog, const float* __restrict__ bob,
             const float* __restrict__ bom, const float* __restrict__ bov)
{
    __shared__ float B0[ROW], B1[ROW];     // 2 x 32 KB
    const int t = threadIdx.x;
    const int rowb = blockIdx.x;           // b*128 + i
    const int b = rowb >> 7, i = rowb & 127;
    const int im = (i == 0)    ? 1    : i - 1;   // reflect
    const int ip = (i == HH-1) ? HH-2 : i + 1;
    const _Float16* fb  = f + (size_t)b * (HH*ROW);
    const _Float16* frm = fb + (size_t)im * ROW;
    const _Float16* fr0 = fb + (size_t)i  * ROW;
    const _Float16* frp = fb + (size_t)ip * ROW;
    const float* grow = g + (size_t)rowb * ROW;

    const int lane = t & 63;
    const int srcm = (lane & 48) | ((lane - 1) & 15);   // c-group lane-1 (cyclic)
    const int srcp = (lane & 48) | ((lane + 1) & 15);   // c-group lane+1 (cyclic)
    const int w0 = t >> 4, c0 = (t & 15) << 2;
    const int qch[2] = { t*4, t*4 + 4096 };
    const int wch[2] = { w0, w0 + 64 };

    // ---- stage f[i-1]->B0, f[i+1]->B1
    #pragma unroll
    for (int k = 0; k < 2; ++k) {
        half4v vm = *(const half4v*)(frm + qch[k]);
        half4v vp = *(const half4v*)(frp + qch[k]);
        floatx4 a = { (float)vm[0], (float)vm[1], (float)vm[2], (float)vm[3] };
        floatx4 p = { (float)vp[0], (float)vp[1], (float)vp[2], (float)vp[3] };
        *(floatx4*)(B0 + qch[k]) = a;
        *(floatx4*)(B1 + qch[k]) = p;
    }
    __syncthreads();

    // ---- Sobel partials from rows i+-1 (REFLECT in W)
    floatx4 Bx4[2], dxp4[2];
    #pragma unroll
    for (int k = 0; k < 2; ++k) {
        int w = wch[k];
        int wm = (w == 0)    ? 1      : w - 1;
        int wp = (w == WW-1) ? WW - 2 : w + 1;
        floatx4 am = *(const floatx4*)(B0 + wm*CC + c0);
        floatx4 a0 = *(const floatx4*)(B0 + w *CC + c0);
        floatx4 ap = *(const floatx4*)(B0 + wp*CC + c0);
        floatx4 bm = *(const floatx4*)(B1 + wm*CC + c0);
        floatx4 b0 = *(const floatx4*)(B1 + w *CC + c0);
        floatx4 bp = *(const floatx4*)(B1 + wp*CC + c0);
        floatx4 dy = (bm + 2.f*b0 + bp) - (am + 2.f*a0 + ap);
        Bx4[k]  = 0.2f / (dy*dy*0.25f + 1.f);      // Dx*DT
        dxp4[k] = (ap - am) + (bp - bm);
    }
    __syncthreads();

    // ---- stage f[i]->B0 (= h_0), g->B1
    #pragma unroll
    for (int k = 0; k < 2; ++k) {
        half4v v0 = *(const half4v*)(fr0 + qch[k]);
        floatx4 fv = { (float)v0[0], (float)v0[1], (float)v0[2], (float)v0[3] };
        *(floatx4*)(B0 + qch[k]) = fv;
        *(floatx4*)(B1 + qch[k]) = *(const floatx4*)(grow + qch[k]);
    }
    __syncthreads();

    // ---- coefficients (all loop-state in registers as float4)
    floatx4 P4[2], R4[2], Q4[2], cH0[2], cEE[2], cF[2], h4[2], h04[2];
    #pragma unroll
    for (int k = 0; k < 2; ++k) {
        int w = wch[k];
        int wm = (w == 0)    ? 1      : w - 1;     // reflect (sobel dx)
        int wp = (w == WW-1) ? WW - 2 : w + 1;
        int wl = (w + WW - 1) & (WW - 1);          // cyclic (rolls)
        int wr = (w + 1) & (WW - 1);
        floatx4 fm = *(const floatx4*)(B0 + wm*CC + c0);
        floatx4 fv = *(const floatx4*)(B0 + w *CC + c0);
        floatx4 fp = *(const floatx4*)(B0 + wp*CC + c0);
        floatx4 dx = dxp4[k] + 2.f*(fp - fm);
        floatx4 By = 0.2f / (dx*dx*0.25f + 1.f);   // Dy*DT
        floatx4 Bx = Bx4[k];
        floatx4 gv = *(const floatx4*)(B1 + w *CC + c0);
        floatx4 gl = *(const floatx4*)(B1 + wl*CC + c0);
        floatx4 gr = *(const floatx4*)(B1 + wr*CC + c0);
        float gdm = __shfl(gv[3], srcm, 64);       // g[c0-1] from lane-1
        float gup = __shfl(gv[0], srcp, 64);       // g[c0+4] from lane+1
        floatx4 gd = { gdm, gv[0], gv[1], gv[2] };
        floatx4 gu = { gv[1], gv[2], gv[3], gup };
        floatx4 E  = ((gl - gr) + (gd - gu)) * 0.1f;     // (ux+vy)*DT
        floatx4 A  = gv * 0.2f;                          // g*DT
        floatx4 Dd = 1.f / (1.f + 2.f*Bx + 2.f*By);
        cH0[k] = 2.f*Dd - 1.f;            // == Dd*(1-2Bx-2By)
        cEE[k] = -2.f * E * Dd;
        P4[k]  = 2.f * Bx * Dd;
        R4[k]  = 2.f * By * Dd;
        Q4[k]  = A * Dd;
        cF[k]  = 0.4f * Dd * fv;          // Dd * 2*DT*f
        h4[k] = fv; h04[k] = fv;
    }
    __syncthreads();                      // g reads done before loop writes B1

    // loop-invariant LDS offsets (W-direction only; C via shfl)
    int oWl[2], oWr[2];
    #pragma unroll
    for (int k = 0; k < 2; ++k) {
        int w = wch[k];
        oWl[k] = ((w + WW - 1) & (WW - 1))*CC + c0;
        oWr[k] = ((w + 1) & (WW - 1))*CC + c0;
    }

    // ---- K=5 diffusion, h ping-pong B0 -> B1 -> B0 ...
    float* cur = B0;
    float* oth = B1;
    for (int it = 0; it < 5; ++it) {
        #pragma unroll
        for (int k = 0; k < 2; ++k) {
            floatx4 hl = *(const floatx4*)(cur + oWl[k]);
            floatx4 hr = *(const floatx4*)(cur + oWr[k]);
            floatx4 hv = h4[k];
            float hdm = __shfl(hv[3], srcm, 64);
            float hup = __shfl(hv[0], srcp, 64);
            floatx4 hd = { hdm, hv[0], hv[1], hv[2] };
            floatx4 hu = { hv[1], hv[2], hv[3], hup };
            floatx4 hn = cH0[k]*h04[k] + cEE[k]*hv
                       + P4[k]*(hl + hr) + R4[k]*(hd + hu)
                       + Q4[k]*((hr - hl) + (hu - hd)) + cF[k];
            *(floatx4*)(oth + qch[k]) = hn;
            h04[k] = hv; h4[k] = hn;
        }
        __syncthreads();
        float* tmp = cur; cur = oth; oth = tmp;
    }

    // ---- epilogue: relu(bn_o(h)) from registers, float4 stores
    floatx4 gg = *(const floatx4*)(bog + c0);
    floatx4 vv = *(const floatx4*)(bov + c0);
    floatx4 bb = *(const floatx4*)(bob + c0);
    floatx4 mm = *(const floatx4*)(bom + c0);
    floatx4 s4, bi4;
    #pragma unroll
    for (int j = 0; j < 4; ++j) s4[j] = gg[j] * rsqrtf(vv[j] + 1e-3f);
    bi4 = bb - mm*s4;
    float* op = out + (size_t)rowb * ROW;
    #pragma unroll
    for (int k = 0; k < 2; ++k) {
        floatx4 rr = h4[k]*s4 + bi4;
        #pragma unroll
        for (int j = 0; j < 4; ++j) rr[j] = fmaxf(0.f, rr[j]);
        *(floatx4*)(op + qch[k]) = rr;
    }
}

// ---------------------------------------------------------------------------
extern "C" void kernel_launch(void* const* d_in, const int* in_sizes, int n_in,
                              void* d_out, int out_size, void* d_ws, size_t ws_size,
                              hipStream_t stream)
{
    const float* x    = (const float*)d_in[0];
    const float* f_w  = (const float*)d_in[1];
    const float* g_w  = (const float*)d_in[2];
    const float* bnf_g = (const float*)d_in[3];
    const float* bnf_b = (const float*)d_in[4];
    const float* bnf_m = (const float*)d_in[5];
    const float* bnf_v = (const float*)d_in[6];
    const float* bng_g = (const float*)d_in[7];
    const float* bng_b = (const float*)d_in[8];
    const float* bng_m = (const float*)d_in[9];
    const float* bng_v = (const float*)d_in[10];
    const float* bno_g = (const float*)d_in[11];
    const float* bno_b = (const float*)d_in[12];
    const float* bno_m = (const float*)d_in[13];
    const float* bno_v = (const float*)d_in[14];

    float* out = (float*)d_out;
    const size_t N = (size_t)16 * HH * WW * CC;   // 16,777,216
    _Float16* y2   = (_Float16*)d_ws;             // N halfs (32 MB)
    _Float16* fbuf = y2 + N;                      // N halfs
    _Float16* W2f  = y2 + 2*N;                    // 36864 halfs
    _Float16* W2g  = W2f + 36864;

    repack_w<<<288, 256, 0, stream>>>(f_w, g_w, W2f, W2g);
    // conv1: stage relu(bn_f(x)) inline; write f16 f + fused y2=relu(bn_g(f))
    conv_mfma<1,1><<<1024, 256, 0, stream>>>(x, W2f, fbuf, nullptr, y2,
                                             bnf_g, bnf_b, bnf_m, bnf_v,
                                             bng_g, bng_b, bng_m, bng_v);
    // conv2: plain f16 staging from y2; write fp32 g to output slot 1
    conv_mfma<0,0><<<1024, 256, 0, stream>>>(y2, W2g, nullptr, out + N, nullptr,
                                             nullptr, nullptr, nullptr, nullptr,
                                             nullptr, nullptr, nullptr, nullptr);
    // diffusion + bn_o + relu -> output slot 0
    diffuse<<<2048, 1024, 0, stream>>>(fbuf, out + N, out, bno_g, bno_b, bno_m, bno_v);
}